// Round 2
// baseline (386.824 us; speedup 1.0000x reference)
//
#include <hip/hip_runtime.h>
#include <math.h>

#define NDIM 128
#define GRIDX 320
#define LN2F 0.69314718055994530942f

// Global/LDS table layout, per 32-dim panel (8192 floats = 32 KB):
//   [0]    xp2[bin][32] float2 = (x_pos[bin],   x_pos[bin+1])
//   [2048] sA [bin][32] float2 = (slope[bin],   slope[bin+1])
//   [4096] sB [bin][32] float2 = (y_pos[bin],   1/bw[bin])
//   [6144] sC [bin][32] float2 = (bh[bin],      bs[bin])
// bank(addr) = (2*(bin*32+dl)) % 32 = 2*dl % 32  -> independent of bin:
// data-dependent bin gathers can NEVER bank-conflict (2-way wave64 = free).

// ---------------- build + ld-zero kernel ----------------
__global__ void rqs_build(const float* __restrict__ sp, float* __restrict__ tab,
                          float* __restrict__ ld, int nrows) {
  if (blockIdx.x >= 2) {
    // zero the logdet accumulator region (replaces hipMemsetAsync node)
    float4 z4 = {0.f, 0.f, 0.f, 0.f};
    const int nf4 = nrows >> 2;
    for (int i = (blockIdx.x - 2) * 256 + threadIdx.x; i < nf4;
         i += (gridDim.x - 2) * 256)
      ((float4*)ld)[i] = z4;
    return;
  }
  // stage this block's 64 dims of spline_params into LDS (coalesced)
  __shared__ float lsp[64 * 97];
  const int d0 = blockIdx.x * 64;
  for (int i = threadIdx.x; i < 64 * 97; i += 256) lsp[i] = sp[d0 * 97 + i];
  __syncthreads();
  if (threadIdx.x >= 64) return;

  const int d = d0 + threadIdx.x;
  const float* pp = lsp + threadIdx.x * 97;
  const int pnl = d >> 5, dl = d & 31;
  float2* xp2 = (float2*)(tab + pnl * 8192);
  float2* sA  = (float2*)(tab + pnl * 8192 + 2048);
  float2* sB  = (float2*)(tab + pnl * 8192 + 4096);
  float2* sC  = (float2*)(tab + pnl * 8192 + 6144);

  const float offs = (float)log(expm1(1.0 - 1e-4));  // np.log(np.expm1(1-1e-4))

  float mw = -INFINITY, mh = -INFINITY;
  for (int i = 0; i < 32; ++i) {
    mw = fmaxf(mw, pp[i]);
    mh = fmaxf(mh, pp[32 + i]);
  }
  float sw = 0.f, sh = 0.f;
  for (int i = 0; i < 32; ++i) {
    sw += expf(pp[i] - mw);
    sh += expf(pp[32 + i] - mh);
  }
  // sequential cumsum, identical op order/rounding to reference path
  float cw = 0.f, ch = 0.f;
  float x_i = -5.0f, y_i = -5.0f;
  float t0 = pp[64] + offs;
  float s_i = fmaxf(t0, 0.f) + log1pf(expf(-fabsf(t0))) + 1e-4f;
  for (int i = 0; i < 32; ++i) {
    float w = (expf(pp[i] - mw) / sw) * 9.9968f + 1e-4f;
    float h = (expf(pp[32 + i] - mh) / sh) * 9.9968f + 1e-4f;
    cw += w; ch += h;
    float x_n = -5.0f + cw;
    float y_n = -5.0f + ch;
    float tn = pp[64 + i + 1] + offs;
    float s_n = fmaxf(tn, 0.f) + log1pf(expf(-fabsf(tn))) + 1e-4f;
    float bw = x_n - x_i, bh = y_n - y_i;
    const int o = i * 32 + dl;
    xp2[o] = make_float2(x_i, x_n);
    sA[o]  = make_float2(s_i, s_n);
    sB[o]  = make_float2(y_i, 1.0f / bw);
    sC[o]  = make_float2(bh, bh / bw);
    x_i = x_n; y_i = y_n; s_i = s_n;
  }
}

// ---------------- main kernel ----------------
// block = 256 = 8 rows x 32 dims (panel blockIdx.y). Search levels 1-4 live
// in registers (15 even knots + cndmask tree); only the last level + the
// 3 gathers touch LDS: 4x ds_read_b64 per element, all bank-invariant.
__global__ __launch_bounds__(256, 5)
void rqs_main(const float* __restrict__ x, const float* __restrict__ tab,
              float* __restrict__ y, float* __restrict__ ld, int ntiles) {
  __shared__ float lut[8192];  // 32 KB -> 5 blocks/CU
  const int tid = threadIdx.x;
  const int p = blockIdx.y;
  {
    const float4* src = (const float4*)(tab + (size_t)p * 8192);
    float4* dst = (float4*)lut;
    #pragma unroll
    for (int k = 0; k < 8; ++k) dst[tid + 256 * k] = src[tid + 256 * k];
  }
  __syncthreads();

  const int dl = tid & 31;
  const int rl = tid >> 5;
  const float2* xp2 = (const float2*)lut;
  const float2* sA  = (const float2*)(lut + 2048);
  const float2* sB  = (const float2*)(lut + 4096);
  const float2* sC  = (const float2*)(lut + 6144);

  // register-resident even knots for search levels 1-4
  const float xe2  = xp2[(2  << 5) + dl].x;
  const float xe4  = xp2[(4  << 5) + dl].x;
  const float xe6  = xp2[(6  << 5) + dl].x;
  const float xe8  = xp2[(8  << 5) + dl].x;
  const float xe10 = xp2[(10 << 5) + dl].x;
  const float xe12 = xp2[(12 << 5) + dl].x;
  const float xe14 = xp2[(14 << 5) + dl].x;
  const float xe16 = xp2[(16 << 5) + dl].x;
  const float xe18 = xp2[(18 << 5) + dl].x;
  const float xe20 = xp2[(20 << 5) + dl].x;
  const float xe22 = xp2[(22 << 5) + dl].x;
  const float xe24 = xp2[(24 << 5) + dl].x;
  const float xe26 = xp2[(26 << 5) + dl].x;
  const float xe28 = xp2[(28 << 5) + dl].x;
  const float xe30 = xp2[(30 << 5) + dl].x;

  // tail constants
  const float x_last  = xp2[(31 << 5) + dl].y;
  const float s_first = sA[dl].x;
  const float s_last  = sA[(31 << 5) + dl].y;
  const float y_last  = sB[(31 << 5) + dl].x + sC[(31 << 5) + dl].x;
  const float l2_sf = __log2f(s_first);
  const float l2_sl = __log2f(s_last);

  const long long stride = (long long)GRIDX * 8 * NDIM;
  const float* xin  = x + (long long)(blockIdx.x * 8 + rl) * NDIM + p * 32 + dl;
  float*       yout = y + (long long)(blockIdx.x * 8 + rl) * NDIM + p * 32 + dl;
  float*       ldp  = ld + blockIdx.x * 8 + rl;

  for (int t = blockIdx.x; t < ntiles; t += GRIDX) {
    const float v = *xin;

    // levels 1-4: pure-VALU select tree over register knots
    const bool b1 = (xe16 <= v);
    const float m2 = b1 ? xe24 : xe8;
    const bool b2 = (m2 <= v);
    const float mA = b1 ? xe20 : xe4;
    const float mB = b1 ? xe28 : xe12;
    const float m3 = b2 ? mB : mA;
    const bool b3 = (m3 <= v);
    const float c0 = b3 ? xe6  : xe2;
    const float c1 = b3 ? xe14 : xe10;
    const float c2 = b3 ? xe22 : xe18;
    const float c3 = b3 ? xe30 : xe26;
    const float d0_ = b2 ? c1 : c0;
    const float d1_ = b2 ? c3 : c2;
    const float m4 = b1 ? d1_ : d0_;
    const bool b4 = (m4 <= v);
    const int i = (b1 ? 16 : 0) + (b2 ? 8 : 0) + (b3 ? 4 : 0) + (b4 ? 2 : 0);

    // level 5 + x0 from one ds_read_b64 (bank = 2*dl, conflict-free)
    const int idx2 = (i << 5) + dl;
    const float2 xx = xp2[idx2];
    const bool b5 = (xx.y <= v);
    const float x0v = b5 ? xx.y : xx.x;
    const int gi = idx2 + (b5 ? 32 : 0);

    // 3 gathers: one vaddr + immediate LDS offsets, conflict-free
    const float2 ss = sA[gi];
    const float2 yb = sB[gi];
    const float2 hb = sC[gi];
    const float s0 = ss.x, s1 = ss.y, y0 = yb.x, ibw = yb.y;
    const float bh = hb.x, bs = hb.y;

    float z = (v - x0v) * ibw;
    z = fminf(fmaxf(z, 0.f), 1.f);
    const float zz    = z * z;
    const float z1mz  = z - zz;
    const float omz   = 1.f - z;
    const float sq1mz = omz * omz;
    const float st2   = fmaf(-2.f, bs, s0 + s1);   // s0+s1-2bs
    const float den   = fmaf(st2, z1mz, bs);
    float r = __builtin_amdgcn_rcpf(den);
    r = r * (2.f - den * r);                        // Newton
    float num = bs * zz;
    num = fmaf(s0, z1mz, num);
    num = num * bh;
    float yv = fmaf(num, r, y0);
    float P = s1 * zz;
    P = fmaf(bs, z1mz + z1mz, P);
    P = fmaf(s0, sq1mz, P);
    const float bs2 = bs * bs;
    float arg = (bs2 * P) * (r * r);
    float l2v = __log2f(arg);   // logdet = ln2 * log2(bs^2 * P / den^2)

    // out-of-range tails (~19 of 33.5M elements): wave-voted rare path
    const bool below = (v <= -5.0f);
    const bool above = (v >= x_last);
    if (__builtin_expect(__any(below || above), 0)) {
      const float ye = below ? fmaf(v + 5.0f, s_first, -5.0f)
                             : fmaf(v - x_last, s_last, y_last);
      const float le = below ? l2_sf : l2_sl;
      if (below || above) { yv = ye; l2v = le; }
    }
    *yout = yv;

    // per-row logdet reduce over the 32 lanes of this row
    float sum = l2v;
    sum += __shfl_xor(sum, 1);
    sum += __shfl_xor(sum, 2);
    sum += __shfl_xor(sum, 4);
    sum += __shfl_xor(sum, 8);
    sum += __shfl_xor(sum, 16);
    if (dl == 0) atomicAdd(ldp, sum * LN2F);

    xin += stride; yout += stride; ldp += GRIDX * 8;
  }
}

extern "C" void kernel_launch(void* const* d_in, const int* in_sizes, int n_in,
                              void* d_out, int out_size, void* d_ws, size_t ws_size,
                              hipStream_t stream) {
  const float* x  = (const float*)d_in[0];
  const float* sp = (const float*)d_in[1];
  float* out = (float*)d_out;
  const int n = in_sizes[0] / NDIM;              // 262144
  float* y  = out;
  float* ld = out + (long long)n * NDIM;
  float* tab = (float*)d_ws;                     // 4 panels * 32 KB = 128 KB

  rqs_build<<<dim3(66), dim3(256), 0, stream>>>(sp, tab, ld, n);
  rqs_main<<<dim3(GRIDX, 4), dim3(256), 0, stream>>>(x, tab, y, ld, n / 8);
}

// Round 5
// 265.743 us; speedup vs baseline: 1.4556x; 1.4556x over previous
//
#include <hip/hip_runtime.h>
#include <math.h>

#define NDIM 128
#define GRIDX 384
#define LN2F 0.69314718055994530942f

// Per-panel table layout (float offsets), identical in global ws and LDS:
//   OFF_ODD  [16][32]        odd knots xp[2j+1]           (bank = dl)
//   OFF_SLP  [33][32]        slopes s[k]                  (bank = dl)
//   OFF_SB   float2[32][32]  (y0, 1/bw)                   (bank pair = 2dl)
//   OFF_SC   float2[32][32]  (bh, bs)                     (bank pair = 2dl)
//   OFF_XEV  [16][32]        even knots xp[2k+2], k=15 -> xp[32]  (regs only)
// Every LDS read's bank depends only on dl -> data-dependent bin gathers can
// never bank-conflict (verified round 2: conflict counter ~0).
#define OFF_ODD 0
#define OFF_SLP 512
#define OFF_SB  1568
#define OFF_SC  3616
#define OFF_XEV 5664
#define PST     6176          // panel stride, floats
#define LDS_FLOATS 5664       // staged portion (22,656 B -> 7 blocks/CU)

// ---------------- build + ld-zero kernel ----------------
__global__ void rqs_build(const float* __restrict__ sp, float* __restrict__ tab,
                          float* __restrict__ ld, int nrows) {
  if (blockIdx.x >= 2) {
    float4 z4 = {0.f, 0.f, 0.f, 0.f};
    const int nf4 = nrows >> 2;
    for (int i = (blockIdx.x - 2) * 256 + threadIdx.x; i < nf4;
         i += (gridDim.x - 2) * 256)
      ((float4*)ld)[i] = z4;
    return;
  }
  __shared__ float lsp[64 * 97];
  const int d0 = blockIdx.x * 64;
  for (int i = threadIdx.x; i < 64 * 97; i += 256) lsp[i] = sp[d0 * 97 + i];
  __syncthreads();
  if (threadIdx.x >= 64) return;

  const int d = d0 + threadIdx.x;
  const float* pp = lsp + threadIdx.x * 97;
  const int pnl = d >> 5, dl = d & 31;
  float*  base = tab + (size_t)pnl * PST;
  float*  lodd = base + OFF_ODD;
  float*  slp  = base + OFF_SLP;
  float2* sB   = (float2*)(base + OFF_SB);
  float2* sC   = (float2*)(base + OFF_SC);
  float*  xev  = base + OFF_XEV;

  const float offs = (float)log(expm1(1.0 - 1e-4));  // np.log(np.expm1(1-1e-4))

  float mw = -INFINITY, mh = -INFINITY;
  for (int i = 0; i < 32; ++i) {
    mw = fmaxf(mw, pp[i]);
    mh = fmaxf(mh, pp[32 + i]);
  }
  float sw = 0.f, sh = 0.f;
  for (int i = 0; i < 32; ++i) {
    sw += expf(pp[i] - mw);
    sh += expf(pp[32 + i] - mh);
  }
  // sequential cumsum: identical op order/rounding to the reference
  float cw = 0.f, ch = 0.f;
  float x_i = -5.0f, y_i = -5.0f;
  float t0 = pp[64] + offs;
  float s_i = fmaxf(t0, 0.f) + log1pf(expf(-fabsf(t0))) + 1e-4f;
  for (int i = 0; i < 32; ++i) {
    float w = (expf(pp[i] - mw) / sw) * 9.9968f + 1e-4f;
    float h = (expf(pp[32 + i] - mh) / sh) * 9.9968f + 1e-4f;
    cw += w; ch += h;
    float x_n = -5.0f + cw;
    float y_n = -5.0f + ch;
    float tn = pp[64 + i + 1] + offs;
    float s_n = fmaxf(tn, 0.f) + log1pf(expf(-fabsf(tn))) + 1e-4f;
    float bw = x_n - x_i, bh = y_n - y_i;
    slp[i * 32 + dl] = s_i;
    sB[i * 32 + dl]  = make_float2(y_i, 1.0f / bw);
    sC[i * 32 + dl]  = make_float2(bh, bh / bw);
    if ((i & 1) == 0) lodd[(i >> 1) * 32 + dl] = x_n;      // xp[1],xp[3],...
    else              xev[((i - 1) >> 1) * 32 + dl] = x_n; // xp[2],... i=31 -> xp[32]
    x_i = x_n; y_i = y_n; s_i = s_n;
  }
  slp[32 * 32 + dl] = s_i;  // s[32]
}

// ---------------- main kernel ----------------
// block = 256 = 8 rows x 32 dims, panel = blockIdx.y; 2 rows/thread per iter
// (rows base+rl and base+rl+8) for ILP, plus next-iter x prefetch.
__global__ __launch_bounds__(256, 5)
void rqs_main(const float* __restrict__ x, const float* __restrict__ tab,
              float* __restrict__ y, float* __restrict__ ld, int ntiles) {
  __shared__ float lut[LDS_FLOATS];
  const int tid = threadIdx.x;
  const int p = blockIdx.y;
  {
    const float4* src = (const float4*)(tab + (size_t)p * PST);
    float4* dst = (float4*)lut;
    for (int i = tid; i < LDS_FLOATS / 4; i += 256) dst[i] = src[i];
  }
  const int dl = tid & 31;
  const int rl = tid >> 5;
  // even knots -> registers (global reads, no sync needed)
  const float* xevg = tab + (size_t)p * PST + OFF_XEV;
  const float xe2  = xevg[0 * 32 + dl];
  const float xe4  = xevg[1 * 32 + dl];
  const float xe6  = xevg[2 * 32 + dl];
  const float xe8  = xevg[3 * 32 + dl];
  const float xe10 = xevg[4 * 32 + dl];
  const float xe12 = xevg[5 * 32 + dl];
  const float xe14 = xevg[6 * 32 + dl];
  const float xe16 = xevg[7 * 32 + dl];
  const float xe18 = xevg[8 * 32 + dl];
  const float xe20 = xevg[9 * 32 + dl];
  const float xe22 = xevg[10 * 32 + dl];
  const float xe24 = xevg[11 * 32 + dl];
  const float xe26 = xevg[12 * 32 + dl];
  const float xe28 = xevg[13 * 32 + dl];
  const float xe30 = xevg[14 * 32 + dl];
  const float x_last = xevg[15 * 32 + dl];   // xp[32]
  __syncthreads();

  const float*  lodd = lut + OFF_ODD;
  const float*  slp  = lut + OFF_SLP;
  const float2* sB   = (const float2*)(lut + OFF_SB);
  const float2* sC   = (const float2*)(lut + OFF_SC);

  auto proc = [&](float v, float& yv, float& l2v) {
    // levels 1-4: pure-VALU select tree over register even knots
    const bool b1 = (xe16 <= v);
    float x0e = b1 ? xe16 : -5.0f;
    const float m2 = b1 ? xe24 : xe8;
    const bool b2 = (m2 <= v);
    x0e = b2 ? m2 : x0e;
    const float mA = b1 ? xe20 : xe4;
    const float mB = b1 ? xe28 : xe12;
    const float m3 = b2 ? mB : mA;
    const bool b3 = (m3 <= v);
    x0e = b3 ? m3 : x0e;
    const float c0 = b3 ? xe6  : xe2;
    const float c1 = b3 ? xe14 : xe10;
    const float c2 = b3 ? xe22 : xe18;
    const float c3 = b3 ? xe30 : xe26;
    const float d0_ = b2 ? c1 : c0;
    const float d1_ = b2 ? c3 : c2;
    const float m4 = b1 ? d1_ : d0_;
    const bool b4 = (m4 <= v);
    x0e = b4 ? m4 : x0e;
    const int i = (b1 ? 16 : 0) + (b2 ? 8 : 0) + (b3 ? 4 : 0) + (b4 ? 2 : 0);
    // level 5: one conflict-free ds_read_b32 of the odd knot
    const float xodd = lodd[(i << 4) + dl];
    const bool b5 = (xodd <= v);
    const float x0v = b5 ? xodd : x0e;
    const int gidx = ((i + (b5 ? 1 : 0)) << 5) + dl;
    // gathers: bank-invariant
    const float s0 = slp[gidx];
    const float s1 = slp[gidx + 32];
    const float2 yb = sB[gidx];
    const float2 hb = sC[gidx];
    const float y0 = yb.x, ibw = yb.y, bh = hb.x, bs = hb.y;

    float z = (v - x0v) * ibw;
    z = fminf(fmaxf(z, 0.f), 1.f);
    const float zz    = z * z;
    const float z1mz  = z - zz;
    const float omz   = 1.f - z;
    const float sq1mz = omz * omz;
    const float st2   = fmaf(-2.f, bs, s0 + s1);
    const float den   = fmaf(st2, z1mz, bs);
    float r = __builtin_amdgcn_rcpf(den);
    r = r * (2.f - den * r);                    // Newton
    float num = bs * zz;
    num = fmaf(s0, z1mz, num);
    num = num * bh;
    yv = fmaf(num, r, y0);
    float P = s1 * zz;
    P = fmaf(bs, z1mz + z1mz, P);
    P = fmaf(s0, sq1mz, P);
    const float arg = (bs * bs * P) * (r * r);
    l2v = __log2f(arg);   // logdet = ln2 * log2(bs^2 * P / den^2)

    // out-of-range tails (~19 of 33.5M): wave-voted rare path, consts from LDS
    const bool below = (v <= -5.0f);
    const bool above = (v >= x_last);
    if (__builtin_expect(__any(below || above), 0)) {
      const float s_first = slp[dl];
      const float s_lastv = slp[32 * 32 + dl];
      const float2 yb31 = sB[(31 << 5) + dl];
      const float2 hb31 = sC[(31 << 5) + dl];
      const float y_last = yb31.x + hb31.x;
      const float ye = below ? fmaf(v + 5.0f, s_first, -5.0f)
                             : fmaf(v - x_last, s_lastv, y_last);
      const float le = below ? __log2f(s_first) : __log2f(s_lastv);
      if (below || above) { yv = ye; l2v = le; }
    }
  };

  const int STRD = GRIDX * 16 * NDIM;           // float stride per loop iter
  int off0 = (blockIdx.x * 16 + rl) * NDIM + p * 32 + dl;
  int off1 = off0 + 8 * NDIM;
  int row0 = blockIdx.x * 16 + rl;
  float v0 = x[off0], v1 = x[off1];

  for (int t = blockIdx.x; t < ntiles; t += GRIDX) {
    const float cv0 = v0, cv1 = v1;
    if (t + GRIDX < ntiles) {                   // block-uniform prefetch
      v0 = x[off0 + STRD];
      v1 = x[off1 + STRD];
    }
    float yv0, l20, yv1, l21;
    proc(cv0, yv0, l20);
    proc(cv1, yv1, l21);
    y[off0] = yv0;
    y[off1] = yv1;

    float sA_ = l20, sBr = l21;
    sA_ += __shfl_xor(sA_, 1);  sBr += __shfl_xor(sBr, 1);
    sA_ += __shfl_xor(sA_, 2);  sBr += __shfl_xor(sBr, 2);
    sA_ += __shfl_xor(sA_, 4);  sBr += __shfl_xor(sBr, 4);
    sA_ += __shfl_xor(sA_, 8);  sBr += __shfl_xor(sBr, 8);
    sA_ += __shfl_xor(sA_, 16); sBr += __shfl_xor(sBr, 16);
    if (dl == 0) {
      atomicAdd(ld + row0,     sA_ * LN2F);
      atomicAdd(ld + row0 + 8, sBr * LN2F);
    }
    off0 += STRD; off1 += STRD; row0 += GRIDX * 16;
  }
}

extern "C" void kernel_launch(void* const* d_in, const int* in_sizes, int n_in,
                              void* d_out, int out_size, void* d_ws, size_t ws_size,
                              hipStream_t stream) {
  const float* x  = (const float*)d_in[0];
  const float* sp = (const float*)d_in[1];
  float* out = (float*)d_out;
  const int n = in_sizes[0] / NDIM;              // 262144
  float* y  = out;
  float* ld = out + (long long)n * NDIM;
  float* tab = (float*)d_ws;                     // 4 * 6176 * 4 B = 98,816 B

  rqs_build<<<dim3(66), dim3(256), 0, stream>>>(sp, tab, ld, n);
  rqs_main<<<dim3(GRIDX, 4), dim3(256), 0, stream>>>(x, tab, y, ld, n / 16);
}